// Round 1
// baseline (10034.103 us; speedup 1.0000x reference)
//
#include <hip/hip_runtime.h>
#include <cstdint>

#define B_SZ 256
#define T_SEQ 512
#define I_SZ 256
#define H_SZ 512
#define O_SZ 256

typedef short shortx8 __attribute__((ext_vector_type(8)));
typedef float floatx4 __attribute__((ext_vector_type(4)));

__device__ __forceinline__ unsigned short f2bf(float f) {
  uint32_t u = __float_as_uint(f);
  u = u + 0x7fffu + ((u >> 16) & 1u);   // RNE
  return (unsigned short)(u >> 16);
}
__device__ __forceinline__ float bf2f(unsigned short h) {
  return __uint_as_float(((uint32_t)h) << 16);
}
__device__ __forceinline__ float sigm(float x) { return 1.0f / (1.0f + __expf(-x)); }
__device__ __forceinline__ float tanh_fast(float x) {
  x = fminf(15.0f, fmaxf(-15.0f, x));
  float e = __expf(2.0f * x);
  return (e - 1.0f) / (e + 1.0f);
}

// ---------------------------------------------------------------------------
// Phase 0: pack weights.
//   bias_all[2048]           : fp32, gate-major (f,i,g,o) x 512
//   Wx_bf [256][2048]        : bf16, x-projection weights
//   Whfrag[cg][g][nt][ks][lane][j] : bf16, recurrent weights in exact MFMA
//       B-fragment order: B[k = ks*32 + (lane>>4)*8 + j][n = lane&15],
//       gate col = g*512 + cg*32 + nt*16 + n.
// ---------------------------------------------------------------------------
__global__ __launch_bounds__(256) void pack_kernel(
    const float* __restrict__ Wf, const float* __restrict__ Wi,
    const float* __restrict__ Wc, const float* __restrict__ Wo,
    const float* __restrict__ bf, const float* __restrict__ bi,
    const float* __restrict__ bc, const float* __restrict__ bo,
    unsigned short* __restrict__ whf, unsigned short* __restrict__ wx,
    float* __restrict__ bias) {
  int idx = blockIdx.x * 256 + threadIdx.x;
  if (idx < 2048) {
    int g = idx >> 9, hid = idx & 511;
    const float* bp = (g == 0) ? bf : (g == 1) ? bi : (g == 2) ? bc : bo;
    bias[idx] = bp[hid];
  }
  int i2 = idx - 2048;
  if (i2 >= 0 && i2 < 256 * 2048) {
    int k = i2 >> 11, col = i2 & 2047, g = col >> 9, hid = col & 511;
    const float* Wp = (g == 0) ? Wf : (g == 1) ? Wi : (g == 2) ? Wc : Wo;
    wx[i2] = f2bf(Wp[k * 512 + hid]);
  }
  int i3 = i2 - 256 * 2048;
  if (i3 >= 0 && i3 < 1048576) {
    int j = i3 & 7, l = (i3 >> 3) & 63, ks = (i3 >> 9) & 15;
    int nt = (i3 >> 13) & 1, g = (i3 >> 14) & 3, cg = (i3 >> 16) & 15;
    int k = ks * 32 + (l >> 4) * 8 + j;
    int hid = cg * 32 + nt * 16 + (l & 15);
    const float* Wp = (g == 0) ? Wf : (g == 1) ? Wi : (g == 2) ? Wc : Wo;
    whf[i3] = f2bf(Wp[(256 + k) * 512 + hid]);
  }
}

// Init: zero flags (set flag[bg][0]=16), zero h-exchange slot 0, zero c state.
__global__ __launch_bounds__(256) void init_kernel(int* flags, uint32_t* h_ex,
                                                   float* c_gl) {
  int idx = blockIdx.x * 256 + threadIdx.x;
  if (idx < 16 * 513) flags[idx] = ((idx % 513) == 0) ? 16 : 0;
  if (idx < 65536) h_ex[idx] = 0u;
  if (idx < 131072) c_gl[idx] = 0.0f;
}

// ---------------------------------------------------------------------------
// Phase 1: Z[b*TC+tt][col] = (x_{t0+tt,b} @ Wx)[col] + bias[col]   (bf16 out)
// 128x128 tile, K=256 in 4x BK=64 stages. fp32 X is converted to bf16 in the
// A-staging path (no separate convert pass).
// ---------------------------------------------------------------------------
__global__ __launch_bounds__(256) void gemm_x(
    const float* __restrict__ X, const unsigned short* __restrict__ Wx,
    const float* __restrict__ bias, unsigned short* __restrict__ Z,
    int t0, int TC, int tcs) {
  __shared__ unsigned short lds_a[128 * 72];  // [row][k] pad 72
  __shared__ unsigned short lds_b[128 * 72];  // [n][k]   pad 72
  const int tid = threadIdx.x;
  const int mt = blockIdx.x >> 4, ntb = blockIdx.x & 15;
  const int n0 = ntb * 128;
  const int w = tid >> 6, l = tid & 63, q = l >> 4, n15 = l & 15;

  floatx4 acc[2][8];
#pragma unroll
  for (int a = 0; a < 2; ++a)
#pragma unroll
    for (int nb = 0; nb < 8; ++nb) acc[a][nb] = (floatx4){0.f, 0.f, 0.f, 0.f};

  const int i_row = tid >> 1, half = tid & 1;
  const int Mr = mt * 128 + i_row;
  const int bb = Mr >> tcs, tt = Mr & (TC - 1);
  const float* asrc = X + ((size_t)(bb * T_SEQ + t0 + tt)) * I_SZ;

  for (int ko = 0; ko < 4; ++ko) {
    const int k0 = ko * 64;
    __syncthreads();
    // A stage: 2 threads/row, 32 cols each, fp32 -> bf16
#pragma unroll
    for (int u = 0; u < 8; ++u) {
      int kl = half * 32 + u * 4;
      float4 v = *(const float4*)(asrc + k0 + kl);
      uint2 pk;
      pk.x = (uint32_t)f2bf(v.x) | ((uint32_t)f2bf(v.y) << 16);
      pk.y = (uint32_t)f2bf(v.z) | ((uint32_t)f2bf(v.w) << 16);
      *(uint2*)(lds_a + i_row * 72 + kl) = pk;
    }
    // B stage: transpose Wx[k][n] -> lds_b[n][k]
    {
      int kb = tid >> 4, n8 = (tid & 15) * 8;
#pragma unroll
      for (int p = 0; p < 4; ++p) {
        int kl = p * 16 + kb;
        const unsigned short* srcw = Wx + (size_t)(k0 + kl) * 2048 + n0 + n8;
        uint4 v = *(const uint4*)srcw;
        unsigned short* db = lds_b + kl;
        db[(n8 + 0) * 72] = (unsigned short)(v.x & 0xffff);
        db[(n8 + 1) * 72] = (unsigned short)(v.x >> 16);
        db[(n8 + 2) * 72] = (unsigned short)(v.y & 0xffff);
        db[(n8 + 3) * 72] = (unsigned short)(v.y >> 16);
        db[(n8 + 4) * 72] = (unsigned short)(v.z & 0xffff);
        db[(n8 + 5) * 72] = (unsigned short)(v.z >> 16);
        db[(n8 + 6) * 72] = (unsigned short)(v.w & 0xffff);
        db[(n8 + 7) * 72] = (unsigned short)(v.w >> 16);
      }
    }
    __syncthreads();
#pragma unroll
    for (int kk = 0; kk < 2; ++kk) {
      shortx8 af[2], bfr[8];
#pragma unroll
      for (int a = 0; a < 2; ++a) {
        int row = (w * 2 + a) * 16 + n15;
        af[a] = *(const shortx8*)(lds_a + row * 72 + kk * 32 + q * 8);
      }
#pragma unroll
      for (int nb = 0; nb < 8; ++nb) {
        int col = nb * 16 + n15;
        bfr[nb] = *(const shortx8*)(lds_b + col * 72 + kk * 32 + q * 8);
      }
#pragma unroll
      for (int a = 0; a < 2; ++a)
#pragma unroll
        for (int nb = 0; nb < 8; ++nb)
          acc[a][nb] = __builtin_amdgcn_mfma_f32_16x16x32_bf16(
              af[a], bfr[nb], acc[a][nb], 0, 0, 0);
    }
  }
  // epilogue: + bias, bf16 store (D layout: row=4q+r, col=n15 within tile)
#pragma unroll
  for (int a = 0; a < 2; ++a) {
#pragma unroll
    for (int nb = 0; nb < 8; ++nb) {
      int colg = n0 + nb * 16 + n15;
      float bv = bias[colg];
      floatx4 v = acc[a][nb];
#pragma unroll
      for (int r = 0; r < 4; ++r) {
        int Mrow = mt * 128 + (w * 2 + a) * 16 + q * 4 + r;
        Z[(size_t)Mrow * 2048 + colg] = f2bf(v[r] + bv);
      }
    }
  }
}

// ---------------------------------------------------------------------------
// Phase 2: recurrent chunk. 256 blocks = 16 bg x 16 cg. Block owns batch rows
// [bg*16,bg*16+16) and hidden cols [cg*32,cg*32+32) (=128 gate cols; wave w =
// gate w in order f,i,g,o). Recurrent weights resident in registers as MFMA
// B-frags. h exchanged via LIC (system-scope stores + flag), layout = MFMA
// A-frag order: hw idx = ((((slot*16+bg)*16+ks)*4+q)*16+m)*8 + j,
// k = ks*32 + q*8 + j.
// ---------------------------------------------------------------------------
__global__ __launch_bounds__(256) void lstm_chunk(
    const unsigned short* __restrict__ Z, const unsigned short* __restrict__ whf,
    uint32_t* h_ex, int* flags, float* c_gl, int t0, int TC) {
  const int tid = threadIdx.x, l = tid & 63, w = tid >> 6, q = l >> 4,
            n15 = l & 15;
  const int bl = blockIdx.x, bg = bl & 15, cg = bl >> 4;

  // resident B fragments: 2 ntiles x 16 ksteps x 4 VGPR = 128 VGPR/lane
  shortx8 Bf[2][16];
#pragma unroll
  for (int nt = 0; nt < 2; ++nt)
#pragma unroll
    for (int ks = 0; ks < 16; ++ks) {
      size_t u4 = ((size_t)(((cg * 4 + w) * 2 + nt) * 16 + ks)) * 64 + l;
      Bf[nt][ks] = *(const shortx8*)(whf + u4 * 8);
    }

  const int m_e = tid >> 4, c2 = (tid & 15) * 2;  // elementwise ownership
  const int b_e = bg * 16 + m_e;
  float cs0 = c_gl[b_e * 512 + cg * 32 + c2];
  float cs1 = c_gl[b_e * 512 + cg * 32 + c2 + 1];

  __shared__ float gl[4][16][32];  // gate exchange (f,i,g,o)[m][c]
  int* flagrow = flags + bg * 513;
  const unsigned short* hhw = (const unsigned short*)h_ex;

  for (int t = t0; t < t0 + TC; ++t) {
    // Z prefetch (independent of flags -> hides HBM latency behind the poll)
    float zv[8];
#pragma unroll
    for (int nt = 0; nt < 2; ++nt)
#pragma unroll
      for (int r = 0; r < 4; ++r) {
        int bb = bg * 16 + q * 4 + r;
        int col = w * 512 + cg * 32 + nt * 16 + n15;
        zv[nt * 4 + r] = bf2f(Z[((size_t)bb * TC + (t - t0)) * 2048 + col]);
      }
    // wait for all 16 producers of h_t in this batch group
    while (__hip_atomic_load(flagrow + t, __ATOMIC_RELAXED,
                             __HIP_MEMORY_SCOPE_SYSTEM) < 16) {}
    __builtin_amdgcn_fence(__ATOMIC_ACQUIRE, "");  // inv L1/L2 -> fresh h

    const int slot = t & 1;
    shortx8 Af[16];
#pragma unroll
    for (int ks = 0; ks < 16; ++ks) {
      size_t u4 = ((((size_t)slot * 16 + bg) * 16 + ks) * 4 + q) * 16 + n15;
      Af[ks] = *(const shortx8*)(hhw + u4 * 8);
    }
    floatx4 a0 = (floatx4){0.f, 0.f, 0.f, 0.f};
    floatx4 a1 = (floatx4){0.f, 0.f, 0.f, 0.f};
#pragma unroll
    for (int ks = 0; ks < 16; ++ks) {
      a0 = __builtin_amdgcn_mfma_f32_16x16x32_bf16(Af[ks], Bf[0][ks], a0, 0, 0, 0);
      a1 = __builtin_amdgcn_mfma_f32_16x16x32_bf16(Af[ks], Bf[1][ks], a1, 0, 0, 0);
    }
    // gate nonlinearity, publish to LDS
#pragma unroll
    for (int i = 0; i < 8; ++i) {
      float x = ((i < 4) ? a0[i & 3] : a1[i & 3]) + zv[i];
      float gv = (w == 2) ? tanh_fast(x) : sigm(x);
      gl[w][q * 4 + (i & 3)][(i >> 2) * 16 + n15] = gv;
    }
    __syncthreads();
    {
      float f0 = gl[0][m_e][c2], f1 = gl[0][m_e][c2 + 1];
      float i0 = gl[1][m_e][c2], i1 = gl[1][m_e][c2 + 1];
      float g0 = gl[2][m_e][c2], g1 = gl[2][m_e][c2 + 1];
      float o0 = gl[3][m_e][c2], o1 = gl[3][m_e][c2 + 1];
      cs0 = f0 * cs0 + i0 * g0;
      cs1 = f1 * cs1 + i1 * g1;
      float h0 = o0 * tanh_fast(cs0);
      float h1 = o1 * tanh_fast(cs1);
      uint32_t hw = (uint32_t)f2bf(h0) | ((uint32_t)f2bf(h1) << 16);
      // k = cg*32 + c2 -> ks=cg, q'=c2>>3, j=c2&7 (even)
      size_t widx = ((((size_t)((t + 1) & 1) * 16 + bg) * 16 + cg) * 4 +
                     (c2 >> 3)) * 64 + (size_t)m_e * 4 + ((c2 & 7) >> 1);
      __hip_atomic_store(h_ex + widx, hw, __ATOMIC_RELAXED,
                         __HIP_MEMORY_SCOPE_SYSTEM);
    }
    asm volatile("s_waitcnt vmcnt(0)" ::: "memory");  // own stores at LIC
    __syncthreads();                                   // all 256 stores done
    if (tid == 0)
      __hip_atomic_fetch_add(flagrow + t + 1, 1, __ATOMIC_RELEASE,
                             __HIP_MEMORY_SCOPE_SYSTEM);
  }
  c_gl[b_e * 512 + cg * 32 + c2] = cs0;
  c_gl[b_e * 512 + cg * 32 + c2 + 1] = cs1;
}

// ---------------------------------------------------------------------------
// Phase 3: logits = h_512 @ Wout + bout; log_softmax. One block per batch row.
// ---------------------------------------------------------------------------
__global__ __launch_bounds__(256) void out_kernel(
    const uint32_t* __restrict__ h_ex, const float* __restrict__ Wout,
    const float* __restrict__ bout, float* __restrict__ out) {
  const int b = blockIdx.x, tid = threadIdx.x;
  __shared__ float hrow[512];
  if (tid < 64) {
    int ks = tid >> 2, qq = tid & 3;
    const uint4* h4 = (const uint4*)h_ex;  // slot 0 holds h_512 (512 even)
    uint4 v = h4[((((size_t)(b >> 4)) * 16 + ks) * 4 + qq) * 16 + (b & 15)];
    uint32_t u[4] = {v.x, v.y, v.z, v.w};
#pragma unroll
    for (int d = 0; d < 4; ++d) {
      hrow[ks * 32 + qq * 8 + d * 2] = bf2f((unsigned short)(u[d] & 0xffff));
      hrow[ks * 32 + qq * 8 + d * 2 + 1] = bf2f((unsigned short)(u[d] >> 16));
    }
  }
  __syncthreads();
  float acc = bout[tid];
  for (int k = 0; k < 512; ++k) acc += hrow[k] * Wout[k * 256 + tid];
  __shared__ float red[256];
  red[tid] = acc;
  __syncthreads();
  for (int s = 128; s > 0; s >>= 1) {
    if (tid < s) red[tid] = fmaxf(red[tid], red[tid + s]);
    __syncthreads();
  }
  float mx = red[0];
  __syncthreads();
  red[tid] = __expf(acc - mx);
  __syncthreads();
  for (int s = 128; s > 0; s >>= 1) {
    if (tid < s) red[tid] += red[tid + s];
    __syncthreads();
  }
  out[b * 256 + tid] = acc - mx - logf(red[0]);
}

// ---------------------------------------------------------------------------
extern "C" void kernel_launch(void* const* d_in, const int* in_sizes, int n_in,
                              void* d_out, int out_size, void* d_ws,
                              size_t ws_size, hipStream_t stream) {
  const float* X = (const float*)d_in[0];
  const float* Wf = (const float*)d_in[1];
  const float* bf = (const float*)d_in[2];
  const float* Wi = (const float*)d_in[3];
  const float* bi = (const float*)d_in[4];
  const float* Wc = (const float*)d_in[5];
  const float* bc = (const float*)d_in[6];
  const float* Wo = (const float*)d_in[7];
  const float* bo = (const float*)d_in[8];
  const float* Wout = (const float*)d_in[9];
  const float* bout = (const float*)d_in[10];

  char* ws = (char*)d_ws;
  unsigned short* whf = (unsigned short*)(ws + 0x000000);   // 2 MB
  unsigned short* wxb = (unsigned short*)(ws + 0x200000);   // 1 MB
  float* bias = (float*)(ws + 0x300000);                    // 8 KB
  int* flags = (int*)(ws + 0x302000);                       // 33 KB
  uint32_t* h_ex = (uint32_t*)(ws + 0x320000);              // 512 KB (2 slots)
  float* c_gl = (float*)(ws + 0x3A0000);                    // 512 KB
  unsigned short* Z = (unsigned short*)(ws + 0x420000);     // TC MB

  const size_t fixed = 0x420000;
  int TC = 512;
  while (TC > 16 && fixed + ((size_t)B_SZ * TC * 2048 * 2) > ws_size) TC >>= 1;
  int tcs = 0;
  while ((1 << tcs) < TC) ++tcs;

  pack_kernel<<<(2048 + 256 * 2048 + 1048576 + 255) / 256, 256, 0, stream>>>(
      Wf, Wi, Wc, Wo, bf, bi, bc, bo, whf, wxb, bias);
  init_kernel<<<512, 256, 0, stream>>>(flags, h_ex, c_gl);

  for (int t0 = 0; t0 < T_SEQ; t0 += TC) {
    gemm_x<<<(B_SZ * TC / 128) * 16, 256, 0, stream>>>(X, wxb, bias, Z, t0, TC,
                                                       tcs);
    lstm_chunk<<<256, 256, 0, stream>>>(Z, whf, h_ex, flags, c_gl, t0, TC);
  }
  out_kernel<<<256, 256, 0, stream>>>(h_ex, Wout, bout, (float*)d_out);
}

// Round 2
// 2948.036 us; speedup vs baseline: 3.4037x; 3.4037x over previous
//
#include <hip/hip_runtime.h>
#include <cstdint>

#define B_SZ 256
#define T_SEQ 512
#define I_SZ 256
#define H_SZ 512
#define O_SZ 256

typedef short shortx8 __attribute__((ext_vector_type(8)));
typedef float floatx4 __attribute__((ext_vector_type(4)));

__device__ __forceinline__ unsigned short f2bf(float f) {
  uint32_t u = __float_as_uint(f);
  u = u + 0x7fffu + ((u >> 16) & 1u);   // RNE
  return (unsigned short)(u >> 16);
}
__device__ __forceinline__ float bf2f(unsigned short h) {
  return __uint_as_float(((uint32_t)h) << 16);
}
__device__ __forceinline__ float sigm(float x) { return 1.0f / (1.0f + __expf(-x)); }
__device__ __forceinline__ float tanh_fast(float x) {
  x = fminf(15.0f, fmaxf(-15.0f, x));
  float e = __expf(2.0f * x);
  return (e - 1.0f) / (e + 1.0f);
}

// ---------------------------------------------------------------------------
// Phase 0: pack weights (unchanged from round 1).
// ---------------------------------------------------------------------------
__global__ __launch_bounds__(256) void pack_kernel(
    const float* __restrict__ Wf, const float* __restrict__ Wi,
    const float* __restrict__ Wc, const float* __restrict__ Wo,
    const float* __restrict__ bf, const float* __restrict__ bi,
    const float* __restrict__ bc, const float* __restrict__ bo,
    unsigned short* __restrict__ whf, unsigned short* __restrict__ wx,
    float* __restrict__ bias) {
  int idx = blockIdx.x * 256 + threadIdx.x;
  if (idx < 2048) {
    int g = idx >> 9, hid = idx & 511;
    const float* bp = (g == 0) ? bf : (g == 1) ? bi : (g == 2) ? bc : bo;
    bias[idx] = bp[hid];
  }
  int i2 = idx - 2048;
  if (i2 >= 0 && i2 < 256 * 2048) {
    int k = i2 >> 11, col = i2 & 2047, g = col >> 9, hid = col & 511;
    const float* Wp = (g == 0) ? Wf : (g == 1) ? Wi : (g == 2) ? Wc : Wo;
    wx[i2] = f2bf(Wp[k * 512 + hid]);
  }
  int i3 = i2 - 256 * 2048;
  if (i3 >= 0 && i3 < 1048576) {
    int j = i3 & 7, l = (i3 >> 3) & 63, ks = (i3 >> 9) & 15;
    int nt = (i3 >> 13) & 1, g = (i3 >> 14) & 3, cg = (i3 >> 16) & 15;
    int k = ks * 32 + (l >> 4) * 8 + j;
    int hid = cg * 32 + nt * 16 + (l & 15);
    const float* Wp = (g == 0) ? Wf : (g == 1) ? Wi : (g == 2) ? Wc : Wo;
    whf[i3] = f2bf(Wp[(256 + k) * 512 + hid]);
  }
}

// Init: flags (flag[bg][0]=64 — per-WAVE counting now), h slot 0, c state.
__global__ __launch_bounds__(256) void init_kernel(int* flags, uint32_t* h_ex,
                                                   float* c_gl) {
  int idx = blockIdx.x * 256 + threadIdx.x;
  if (idx < 16 * 513) flags[idx] = ((idx % 513) == 0) ? 64 : 0;
  if (idx < 65536) h_ex[idx] = 0u;
  if (idx < 131072) c_gl[idx] = 0.0f;
}

// ---------------------------------------------------------------------------
// Phase 1: Z = X @ Wx + bias (bf16 out). Unchanged from round 1.
// ---------------------------------------------------------------------------
__global__ __launch_bounds__(256) void gemm_x(
    const float* __restrict__ X, const unsigned short* __restrict__ Wx,
    const float* __restrict__ bias, unsigned short* __restrict__ Z,
    int t0, int TC, int tcs) {
  __shared__ unsigned short lds_a[128 * 72];
  __shared__ unsigned short lds_b[128 * 72];
  const int tid = threadIdx.x;
  const int mt = blockIdx.x >> 4, ntb = blockIdx.x & 15;
  const int n0 = ntb * 128;
  const int w = tid >> 6, l = tid & 63, q = l >> 4, n15 = l & 15;

  floatx4 acc[2][8];
#pragma unroll
  for (int a = 0; a < 2; ++a)
#pragma unroll
    for (int nb = 0; nb < 8; ++nb) acc[a][nb] = (floatx4){0.f, 0.f, 0.f, 0.f};

  const int i_row = tid >> 1, half = tid & 1;
  const int Mr = mt * 128 + i_row;
  const int bb = Mr >> tcs, tt = Mr & (TC - 1);
  const float* asrc = X + ((size_t)(bb * T_SEQ + t0 + tt)) * I_SZ;

  for (int ko = 0; ko < 4; ++ko) {
    const int k0 = ko * 64;
    __syncthreads();
#pragma unroll
    for (int u = 0; u < 8; ++u) {
      int kl = half * 32 + u * 4;
      float4 v = *(const float4*)(asrc + k0 + kl);
      uint2 pk;
      pk.x = (uint32_t)f2bf(v.x) | ((uint32_t)f2bf(v.y) << 16);
      pk.y = (uint32_t)f2bf(v.z) | ((uint32_t)f2bf(v.w) << 16);
      *(uint2*)(lds_a + i_row * 72 + kl) = pk;
    }
    {
      int kb = tid >> 4, n8 = (tid & 15) * 8;
#pragma unroll
      for (int p = 0; p < 4; ++p) {
        int kl = p * 16 + kb;
        const unsigned short* srcw = Wx + (size_t)(k0 + kl) * 2048 + n0 + n8;
        uint4 v = *(const uint4*)srcw;
        unsigned short* db = lds_b + kl;
        db[(n8 + 0) * 72] = (unsigned short)(v.x & 0xffff);
        db[(n8 + 1) * 72] = (unsigned short)(v.x >> 16);
        db[(n8 + 2) * 72] = (unsigned short)(v.y & 0xffff);
        db[(n8 + 3) * 72] = (unsigned short)(v.y >> 16);
        db[(n8 + 4) * 72] = (unsigned short)(v.z & 0xffff);
        db[(n8 + 5) * 72] = (unsigned short)(v.z >> 16);
        db[(n8 + 6) * 72] = (unsigned short)(v.w & 0xffff);
        db[(n8 + 7) * 72] = (unsigned short)(v.w >> 16);
      }
    }
    __syncthreads();
#pragma unroll
    for (int kk = 0; kk < 2; ++kk) {
      shortx8 af[2], bfr[8];
#pragma unroll
      for (int a = 0; a < 2; ++a) {
        int row = (w * 2 + a) * 16 + n15;
        af[a] = *(const shortx8*)(lds_a + row * 72 + kk * 32 + q * 8);
      }
#pragma unroll
      for (int nb = 0; nb < 8; ++nb) {
        int col = nb * 16 + n15;
        bfr[nb] = *(const shortx8*)(lds_b + col * 72 + kk * 32 + q * 8);
      }
#pragma unroll
      for (int a = 0; a < 2; ++a)
#pragma unroll
        for (int nb = 0; nb < 8; ++nb)
          acc[a][nb] = __builtin_amdgcn_mfma_f32_16x16x32_bf16(
              af[a], bfr[nb], acc[a][nb], 0, 0, 0);
    }
  }
#pragma unroll
  for (int a = 0; a < 2; ++a) {
#pragma unroll
    for (int nb = 0; nb < 8; ++nb) {
      int colg = n0 + nb * 16 + n15;
      float bv = bias[colg];
      floatx4 v = acc[a][nb];
#pragma unroll
      for (int r = 0; r < 4; ++r) {
        int Mrow = mt * 128 + (w * 2 + a) * 16 + q * 4 + r;
        Z[(size_t)Mrow * 2048 + colg] = f2bf(v[r] + bv);
      }
    }
  }
}

// ---------------------------------------------------------------------------
// Phase 2: recurrent chunk, fence-free protocol.
//  - h exchange: relaxed SYSTEM atomics only (sc0 sc1 -> LIC, bypass L1/L2;
//    no cached copy can exist, so NO buffer_inv / buffer_wbl2 in the loop).
//  - producer order: h stores -> s_waitcnt vmcnt(0) -> relaxed flag add.
//  - per-WAVE flag adds, threshold 64 (16 blocks x 4 waves per bg).
//  - Bf forced register-resident via inline-asm loads (not rematerializable).
//  - gate-LDS double-buffered by t&1 -> single __syncthreads per step.
// ---------------------------------------------------------------------------
__global__ __launch_bounds__(256, 1) void lstm_chunk(
    const unsigned short* __restrict__ Z, const unsigned short* __restrict__ whf,
    uint32_t* h_ex, int* flags, float* c_gl, int t0, int TC) {
  const int tid = threadIdx.x, l = tid & 63, w = tid >> 6, q = l >> 4,
            n15 = l & 15;
  const int bl = blockIdx.x, bg = bl & 15, cg = bl >> 4;

  // resident B fragments: 2 ntiles x 16 ksteps x 4 VGPR = 128 VGPR/lane.
  // inline-asm loads: compiler cannot rematerialize -> stays in registers.
  shortx8 Bf[2][16];
  {
    const unsigned short* bp =
        whf + ((size_t)(cg * 4 + w) * 2) * 16 * 64 * 8 + (size_t)l * 8;
#pragma unroll
    for (int nt = 0; nt < 2; ++nt)
#pragma unroll
      for (int ks = 0; ks < 16; ++ks) {
        const unsigned short* p = bp + (size_t)(nt * 16 + ks) * 512;
        asm volatile("global_load_dwordx4 %0, %1, off"
                     : "=v"(Bf[nt][ks])
                     : "v"(p)
                     : "memory");
      }
    asm volatile("s_waitcnt vmcnt(0)" ::: "memory");
  }

  const int m_e = tid >> 4, c2 = (tid & 15) * 2;  // elementwise ownership
  const int b_e = bg * 16 + m_e;
  float cs0 = c_gl[b_e * 512 + cg * 32 + c2];
  float cs1 = c_gl[b_e * 512 + cg * 32 + c2 + 1];

  __shared__ float gl[2][4][16][32];  // double-buffered gate exchange
  int* flagrow = flags + bg * 513;
  const unsigned long long* h64 = (const unsigned long long*)h_ex;

  for (int t = t0; t < t0 + TC; ++t) {
    // Z prefetch (cached loads; independent of flag -> hides behind poll)
    float zv[8];
#pragma unroll
    for (int nt = 0; nt < 2; ++nt)
#pragma unroll
      for (int r = 0; r < 4; ++r) {
        int bb = bg * 16 + q * 4 + r;
        int col = w * 512 + cg * 32 + nt * 16 + n15;
        zv[nt * 4 + r] = bf2f(Z[((size_t)bb * TC + (t - t0)) * 2048 + col]);
      }
    // wait for all 64 producer waves of h_t in this batch group
    while (__hip_atomic_load(flagrow + t, __ATOMIC_RELAXED,
                             __HIP_MEMORY_SCOPE_SYSTEM) < 64)
      __builtin_amdgcn_s_sleep(1);
    asm volatile("" ::: "memory");

    const int slot = t & 1;
    shortx8 Af[16];
#pragma unroll
    for (int ks = 0; ks < 16; ++ks) {
      size_t u4 = ((((size_t)slot * 16 + bg) * 16 + ks) * 4 + q) * 16 + n15;
      union { unsigned long long u[2]; shortx8 v; } cvt;
      cvt.u[0] = __hip_atomic_load(h64 + u4 * 2, __ATOMIC_RELAXED,
                                   __HIP_MEMORY_SCOPE_SYSTEM);
      cvt.u[1] = __hip_atomic_load(h64 + u4 * 2 + 1, __ATOMIC_RELAXED,
                                   __HIP_MEMORY_SCOPE_SYSTEM);
      Af[ks] = cvt.v;
    }
    floatx4 a0 = (floatx4){0.f, 0.f, 0.f, 0.f};
    floatx4 a1 = (floatx4){0.f, 0.f, 0.f, 0.f};
#pragma unroll
    for (int ks = 0; ks < 16; ++ks) {
      a0 = __builtin_amdgcn_mfma_f32_16x16x32_bf16(Af[ks], Bf[0][ks], a0, 0, 0, 0);
      a1 = __builtin_amdgcn_mfma_f32_16x16x32_bf16(Af[ks], Bf[1][ks], a1, 0, 0, 0);
    }
    // gate nonlinearity, publish to LDS (buffer t&1)
#pragma unroll
    for (int i = 0; i < 8; ++i) {
      float x = ((i < 4) ? a0[i & 3] : a1[i & 3]) + zv[i];
      float gv = (w == 2) ? tanh_fast(x) : sigm(x);
      gl[slot][w][q * 4 + (i & 3)][(i >> 2) * 16 + n15] = gv;
    }
    __syncthreads();
    {
      float f0 = gl[slot][0][m_e][c2], f1 = gl[slot][0][m_e][c2 + 1];
      float i0 = gl[slot][1][m_e][c2], i1 = gl[slot][1][m_e][c2 + 1];
      float g0 = gl[slot][2][m_e][c2], g1 = gl[slot][2][m_e][c2 + 1];
      float o0 = gl[slot][3][m_e][c2], o1 = gl[slot][3][m_e][c2 + 1];
      cs0 = f0 * cs0 + i0 * g0;
      cs1 = f1 * cs1 + i1 * g1;
      float h0 = o0 * tanh_fast(cs0);
      float h1 = o1 * tanh_fast(cs1);
      uint32_t hw = (uint32_t)f2bf(h0) | ((uint32_t)f2bf(h1) << 16);
      size_t widx = ((((size_t)((t + 1) & 1) * 16 + bg) * 16 + cg) * 4 +
                     (c2 >> 3)) * 64 + (size_t)m_e * 4 + ((c2 & 7) >> 1);
      __hip_atomic_store(h_ex + widx, hw, __ATOMIC_RELAXED,
                         __HIP_MEMORY_SCOPE_SYSTEM);
    }
    // per-wave: drain own store to LIC, then relaxed flag increment
    asm volatile("s_waitcnt vmcnt(0)" ::: "memory");
    if ((tid & 63) == 0)
      __hip_atomic_fetch_add(flagrow + t + 1, 1, __ATOMIC_RELAXED,
                             __HIP_MEMORY_SCOPE_SYSTEM);
  }
  c_gl[b_e * 512 + cg * 32 + c2] = cs0;
  c_gl[b_e * 512 + cg * 32 + c2 + 1] = cs1;
}

// ---------------------------------------------------------------------------
// Phase 3: logits + log_softmax. Unchanged.
// ---------------------------------------------------------------------------
__global__ __launch_bounds__(256) void out_kernel(
    const uint32_t* __restrict__ h_ex, const float* __restrict__ Wout,
    const float* __restrict__ bout, float* __restrict__ out) {
  const int b = blockIdx.x, tid = threadIdx.x;
  __shared__ float hrow[512];
  if (tid < 64) {
    int ks = tid >> 2, qq = tid & 3;
    const uint4* h4 = (const uint4*)h_ex;
    uint4 v = h4[((((size_t)(b >> 4)) * 16 + ks) * 4 + qq) * 16 + (b & 15)];
    uint32_t u[4] = {v.x, v.y, v.z, v.w};
#pragma unroll
    for (int d = 0; d < 4; ++d) {
      hrow[ks * 32 + qq * 8 + d * 2] = bf2f((unsigned short)(u[d] & 0xffff));
      hrow[ks * 32 + qq * 8 + d * 2 + 1] = bf2f((unsigned short)(u[d] >> 16));
    }
  }
  __syncthreads();
  float acc = bout[tid];
  for (int k = 0; k < 512; ++k) acc += hrow[k] * Wout[k * 256 + tid];
  __shared__ float red[256];
  red[tid] = acc;
  __syncthreads();
  for (int s = 128; s > 0; s >>= 1) {
    if (tid < s) red[tid] = fmaxf(red[tid], red[tid + s]);
    __syncthreads();
  }
  float mx = red[0];
  __syncthreads();
  red[tid] = __expf(acc - mx);
  __syncthreads();
  for (int s = 128; s > 0; s >>= 1) {
    if (tid < s) red[tid] += red[tid + s];
    __syncthreads();
  }
  out[b * 256 + tid] = acc - mx - logf(red[0]);
}

// ---------------------------------------------------------------------------
extern "C" void kernel_launch(void* const* d_in, const int* in_sizes, int n_in,
                              void* d_out, int out_size, void* d_ws,
                              size_t ws_size, hipStream_t stream) {
  const float* X = (const float*)d_in[0];
  const float* Wf = (const float*)d_in[1];
  const float* bf = (const float*)d_in[2];
  const float* Wi = (const float*)d_in[3];
  const float* bi = (const float*)d_in[4];
  const float* Wc = (const float*)d_in[5];
  const float* bc = (const float*)d_in[6];
  const float* Wo = (const float*)d_in[7];
  const float* bo = (const float*)d_in[8];
  const float* Wout = (const float*)d_in[9];
  const float* bout = (const float*)d_in[10];

  char* ws = (char*)d_ws;
  unsigned short* whf = (unsigned short*)(ws + 0x000000);   // 2 MB
  unsigned short* wxb = (unsigned short*)(ws + 0x200000);   // 1 MB
  float* bias = (float*)(ws + 0x300000);                    // 8 KB
  int* flags = (int*)(ws + 0x302000);                       // 33 KB
  uint32_t* h_ex = (uint32_t*)(ws + 0x320000);              // 512 KB (2 slots)
  float* c_gl = (float*)(ws + 0x3A0000);                    // 512 KB
  unsigned short* Z = (unsigned short*)(ws + 0x420000);     // TC MB

  const size_t fixed = 0x420000;
  int TC = 512;
  while (TC > 16 && fixed + ((size_t)B_SZ * TC * 2048 * 2) > ws_size) TC >>= 1;
  int tcs = 0;
  while ((1 << tcs) < TC) ++tcs;

  pack_kernel<<<(2048 + 256 * 2048 + 1048576 + 255) / 256, 256, 0, stream>>>(
      Wf, Wi, Wc, Wo, bf, bi, bc, bo, whf, wxb, bias);
  init_kernel<<<512, 256, 0, stream>>>(flags, h_ex, c_gl);

  for (int t0 = 0; t0 < T_SEQ; t0 += TC) {
    gemm_x<<<(B_SZ * TC / 128) * 16, 256, 0, stream>>>(X, wxb, bias, Z, t0, TC,
                                                       tcs);
    lstm_chunk<<<256, 256, 0, stream>>>(Z, whf, h_ex, flags, c_gl, t0, TC);
  }
  out_kernel<<<256, 256, 0, stream>>>(h_ex, Wout, bout, (float*)d_out);
}

// Round 3
// 2946.269 us; speedup vs baseline: 3.4057x; 1.0006x over previous
//
#include <hip/hip_runtime.h>
#include <cstdint>

#define B_SZ 256
#define T_SEQ 512
#define I_SZ 256
#define H_SZ 512
#define O_SZ 256

typedef short shortx8 __attribute__((ext_vector_type(8)));
typedef float floatx4 __attribute__((ext_vector_type(4)));

__device__ __forceinline__ unsigned short f2bf(float f) {
  uint32_t u = __float_as_uint(f);
  u = u + 0x7fffu + ((u >> 16) & 1u);   // RNE
  return (unsigned short)(u >> 16);
}
__device__ __forceinline__ float bf2f(unsigned short h) {
  return __uint_as_float(((uint32_t)h) << 16);
}
__device__ __forceinline__ float sigm(float x) { return 1.0f / (1.0f + __expf(-x)); }
__device__ __forceinline__ float tanh_fast(float x) {
  x = fminf(15.0f, fmaxf(-15.0f, x));
  float e = __expf(2.0f * x);
  return (e - 1.0f) / (e + 1.0f);
}

// ---------------------------------------------------------------------------
// Phase 0: pack weights (unchanged).
//   whf[cg][g][nt][ks][lane][j]: bf16 MFMA B-frag order; per-cg panel is a
//   contiguous 128 KiB block (copied linearly into LDS by lstm_chunk).
// ---------------------------------------------------------------------------
__global__ __launch_bounds__(256) void pack_kernel(
    const float* __restrict__ Wf, const float* __restrict__ Wi,
    const float* __restrict__ Wc, const float* __restrict__ Wo,
    const float* __restrict__ bf, const float* __restrict__ bi,
    const float* __restrict__ bc, const float* __restrict__ bo,
    unsigned short* __restrict__ whf, unsigned short* __restrict__ wx,
    float* __restrict__ bias) {
  int idx = blockIdx.x * 256 + threadIdx.x;
  if (idx < 2048) {
    int g = idx >> 9, hid = idx & 511;
    const float* bp = (g == 0) ? bf : (g == 1) ? bi : (g == 2) ? bc : bo;
    bias[idx] = bp[hid];
  }
  int i2 = idx - 2048;
  if (i2 >= 0 && i2 < 256 * 2048) {
    int k = i2 >> 11, col = i2 & 2047, g = col >> 9, hid = col & 511;
    const float* Wp = (g == 0) ? Wf : (g == 1) ? Wi : (g == 2) ? Wc : Wo;
    wx[i2] = f2bf(Wp[k * 512 + hid]);
  }
  int i3 = i2 - 256 * 2048;
  if (i3 >= 0 && i3 < 1048576) {
    int j = i3 & 7, l = (i3 >> 3) & 63, ks = (i3 >> 9) & 15;
    int nt = (i3 >> 13) & 1, g = (i3 >> 14) & 3, cg = (i3 >> 16) & 15;
    int k = ks * 32 + (l >> 4) * 8 + j;
    int hid = cg * 32 + nt * 16 + (l & 15);
    const float* Wp = (g == 0) ? Wf : (g == 1) ? Wi : (g == 2) ? Wc : Wo;
    whf[i3] = f2bf(Wp[(256 + k) * 512 + hid]);
  }
}

// Init: flags (flag[bg][0]=64), h slot 0 zero, c state zero.
__global__ __launch_bounds__(256) void init_kernel(int* flags, uint32_t* h_ex,
                                                   float* c_gl) {
  int idx = blockIdx.x * 256 + threadIdx.x;
  if (idx < 16 * 513) flags[idx] = ((idx % 513) == 0) ? 64 : 0;
  if (idx < 65536) h_ex[idx] = 0u;
  if (idx < 131072) c_gl[idx] = 0.0f;
}

// ---------------------------------------------------------------------------
// Phase 1: Z = X @ Wx + bias (bf16 out). Unchanged.
// ---------------------------------------------------------------------------
__global__ __launch_bounds__(256) void gemm_x(
    const float* __restrict__ X, const unsigned short* __restrict__ Wx,
    const float* __restrict__ bias, unsigned short* __restrict__ Z,
    int t0, int TC, int tcs) {
  __shared__ unsigned short lds_a[128 * 72];
  __shared__ unsigned short lds_b[128 * 72];
  const int tid = threadIdx.x;
  const int mt = blockIdx.x >> 4, ntb = blockIdx.x & 15;
  const int n0 = ntb * 128;
  const int w = tid >> 6, l = tid & 63, q = l >> 4, n15 = l & 15;

  floatx4 acc[2][8];
#pragma unroll
  for (int a = 0; a < 2; ++a)
#pragma unroll
    for (int nb = 0; nb < 8; ++nb) acc[a][nb] = (floatx4){0.f, 0.f, 0.f, 0.f};

  const int i_row = tid >> 1, half = tid & 1;
  const int Mr = mt * 128 + i_row;
  const int bb = Mr >> tcs, tt = Mr & (TC - 1);
  const float* asrc = X + ((size_t)(bb * T_SEQ + t0 + tt)) * I_SZ;

  for (int ko = 0; ko < 4; ++ko) {
    const int k0 = ko * 64;
    __syncthreads();
#pragma unroll
    for (int u = 0; u < 8; ++u) {
      int kl = half * 32 + u * 4;
      float4 v = *(const float4*)(asrc + k0 + kl);
      uint2 pk;
      pk.x = (uint32_t)f2bf(v.x) | ((uint32_t)f2bf(v.y) << 16);
      pk.y = (uint32_t)f2bf(v.z) | ((uint32_t)f2bf(v.w) << 16);
      *(uint2*)(lds_a + i_row * 72 + kl) = pk;
    }
    {
      int kb = tid >> 4, n8 = (tid & 15) * 8;
#pragma unroll
      for (int p = 0; p < 4; ++p) {
        int kl = p * 16 + kb;
        const unsigned short* srcw = Wx + (size_t)(k0 + kl) * 2048 + n0 + n8;
        uint4 v = *(const uint4*)srcw;
        unsigned short* db = lds_b + kl;
        db[(n8 + 0) * 72] = (unsigned short)(v.x & 0xffff);
        db[(n8 + 1) * 72] = (unsigned short)(v.x >> 16);
        db[(n8 + 2) * 72] = (unsigned short)(v.y & 0xffff);
        db[(n8 + 3) * 72] = (unsigned short)(v.y >> 16);
        db[(n8 + 4) * 72] = (unsigned short)(v.z & 0xffff);
        db[(n8 + 5) * 72] = (unsigned short)(v.z >> 16);
        db[(n8 + 6) * 72] = (unsigned short)(v.w & 0xffff);
        db[(n8 + 7) * 72] = (unsigned short)(v.w >> 16);
      }
    }
    __syncthreads();
#pragma unroll
    for (int kk = 0; kk < 2; ++kk) {
      shortx8 af[2], bfr[8];
#pragma unroll
      for (int a = 0; a < 2; ++a) {
        int row = (w * 2 + a) * 16 + n15;
        af[a] = *(const shortx8*)(lds_a + row * 72 + kk * 32 + q * 8);
      }
#pragma unroll
      for (int nb = 0; nb < 8; ++nb) {
        int col = nb * 16 + n15;
        bfr[nb] = *(const shortx8*)(lds_b + col * 72 + kk * 32 + q * 8);
      }
#pragma unroll
      for (int a = 0; a < 2; ++a)
#pragma unroll
        for (int nb = 0; nb < 8; ++nb)
          acc[a][nb] = __builtin_amdgcn_mfma_f32_16x16x32_bf16(
              af[a], bfr[nb], acc[a][nb], 0, 0, 0);
    }
  }
#pragma unroll
  for (int a = 0; a < 2; ++a) {
#pragma unroll
    for (int nb = 0; nb < 8; ++nb) {
      int colg = n0 + nb * 16 + n15;
      float bv = bias[colg];
      floatx4 v = acc[a][nb];
#pragma unroll
      for (int r = 0; r < 4; ++r) {
        int Mrow = mt * 128 + (w * 2 + a) * 16 + q * 4 + r;
        Z[(size_t)Mrow * 2048 + colg] = f2bf(v[r] + bv);
      }
    }
  }
}

// ---------------------------------------------------------------------------
// Phase 2: recurrent chunk.
//  - Recurrent weights: 128 KiB panel in LDS (no registers to spill; half the
//    per-step B-frag stream is prefetched pre-poll to hide in the wait).
//  - h exchange: rolling slot buffer (slot = t mod TC+1), producer relaxed
//    SYSTEM stores (-> LIC), consumer NORMAL cached loads (write-once
//    addresses per dispatch => no stale line possible; same-XCD consumers
//    share the L2 fill). One system-acquire fence per dispatch for
//    cross-dispatch hygiene.
//  - lane-0 flag poll; per-wave relaxed flag adds (threshold 64).
// ---------------------------------------------------------------------------
__global__ __launch_bounds__(256, 1) void lstm_chunk(
    const unsigned short* __restrict__ Z, const unsigned short* __restrict__ whf,
    uint32_t* h_ex, int* flags, float* c_gl, int t0, int TC) {
  __shared__ unsigned short wlds[65536];   // 128 KiB weight panel
  __shared__ float gl[2][4][16][32];       // 16 KiB gate exchange (dbuf)
  const int tid = threadIdx.x, l = tid & 63, w = tid >> 6, q = l >> 4,
            n15 = l & 15;
  const int bg = blockIdx.x & 15, cg = blockIdx.x >> 4;

  {  // one-time: copy this block's contiguous 128 KiB panel into LDS
    const uint4* src = (const uint4*)(whf + (size_t)cg * 65536);
    uint4* dst = (uint4*)wlds;
#pragma unroll
    for (int i = 0; i < 32; ++i) dst[i * 256 + tid] = src[i * 256 + tid];
  }
  __builtin_amdgcn_fence(__ATOMIC_ACQUIRE, "");  // once: drop stale L1/L2
  __syncthreads();

  const int m_e = tid >> 4, c2 = (tid & 15) * 2;
  const int b_e = bg * 16 + m_e;
  float cs0 = c_gl[b_e * 512 + cg * 32 + c2];
  float cs1 = c_gl[b_e * 512 + cg * 32 + c2 + 1];

  int* flagrow = flags + bg * 513;
  const unsigned short* wb0 = wlds + w * 16384;  // [ks][lane][8], nt=0
  const unsigned short* wb1 = wb0 + 8192;        // nt=1
  const int TCp1 = TC + 1;
  int sr = t0 % TCp1;  // read slot for step t

  for (int t = t0; t < t0 + TC; ++t) {
    int sw = sr + 1;
    if (sw == TCp1) sw = 0;
    // Z prefetch (cached; pre-poll)
    float zv[8];
#pragma unroll
    for (int nt = 0; nt < 2; ++nt)
#pragma unroll
      for (int r = 0; r < 4; ++r)
        zv[nt * 4 + r] =
            bf2f(Z[((size_t)(bg * 16 + q * 4 + r) * TC + (t - t0)) * 2048 +
                   w * 512 + cg * 32 + nt * 16 + n15]);
    // B prefetch ks 0..7 (LDS; pre-poll — hides half the stream in the wait)
    shortx8 bp0[8], bp1[8];
#pragma unroll
    for (int ks = 0; ks < 8; ++ks) {
      bp0[ks] = *(const shortx8*)(wb0 + ks * 512 + l * 8);
      bp1[ks] = *(const shortx8*)(wb1 + ks * 512 + l * 8);
    }
    // wait for all 64 producer waves of h_t (lane 0 only)
    if (l == 0) {
      while (__hip_atomic_load(flagrow + t, __ATOMIC_RELAXED,
                               __HIP_MEMORY_SCOPE_SYSTEM) < 64)
        __builtin_amdgcn_s_sleep(1);
    }
    asm volatile("" ::: "memory");

    // Af: cached coalesced loads from slot sr (write-once address -> fresh)
    const unsigned short* hsl =
        (const unsigned short*)(h_ex + (size_t)sr * 65536);
    shortx8 Af[16];
#pragma unroll
    for (int ks = 0; ks < 16; ++ks)
      Af[ks] = *(const shortx8*)(hsl +
                                 (size_t)(((bg * 16 + ks) * 4 + q) * 16 + n15) * 8);

    floatx4 a0 = (floatx4){0.f, 0.f, 0.f, 0.f};
    floatx4 a1 = (floatx4){0.f, 0.f, 0.f, 0.f};
#pragma unroll
    for (int ks = 0; ks < 8; ++ks) {
      a0 = __builtin_amdgcn_mfma_f32_16x16x32_bf16(Af[ks], bp0[ks], a0, 0, 0, 0);
      a1 = __builtin_amdgcn_mfma_f32_16x16x32_bf16(Af[ks], bp1[ks], a1, 0, 0, 0);
    }
#pragma unroll
    for (int ks = 8; ks < 16; ++ks) {
      shortx8 tb0 = *(const shortx8*)(wb0 + ks * 512 + l * 8);
      shortx8 tb1 = *(const shortx8*)(wb1 + ks * 512 + l * 8);
      a0 = __builtin_amdgcn_mfma_f32_16x16x32_bf16(Af[ks], tb0, a0, 0, 0, 0);
      a1 = __builtin_amdgcn_mfma_f32_16x16x32_bf16(Af[ks], tb1, a1, 0, 0, 0);
    }
    // gate nonlinearity, publish to LDS (buffer t&1)
    const int pb = t & 1;
#pragma unroll
    for (int i = 0; i < 8; ++i) {
      float x = ((i < 4) ? a0[i & 3] : a1[i & 3]) + zv[i];
      float gv = (w == 2) ? tanh_fast(x) : sigm(x);
      gl[pb][w][q * 4 + (i & 3)][(i >> 2) * 16 + n15] = gv;
    }
    __syncthreads();
    {
      float f0 = gl[pb][0][m_e][c2], f1 = gl[pb][0][m_e][c2 + 1];
      float i0 = gl[pb][1][m_e][c2], i1 = gl[pb][1][m_e][c2 + 1];
      float g0 = gl[pb][2][m_e][c2], g1 = gl[pb][2][m_e][c2 + 1];
      float o0 = gl[pb][3][m_e][c2], o1 = gl[pb][3][m_e][c2 + 1];
      cs0 = f0 * cs0 + i0 * g0;
      cs1 = f1 * cs1 + i1 * g1;
      float h0 = o0 * tanh_fast(cs0);
      float h1 = o1 * tanh_fast(cs1);
      uint32_t hw = (uint32_t)f2bf(h0) | ((uint32_t)f2bf(h1) << 16);
      size_t widx = (size_t)sw * 65536 +
                    (size_t)(((bg * 16 + cg) * 4 + (c2 >> 3)) * 16 + m_e) * 4 +
                    ((c2 & 7) >> 1);
      __hip_atomic_store(h_ex + widx, hw, __ATOMIC_RELAXED,
                         __HIP_MEMORY_SCOPE_SYSTEM);
    }
    asm volatile("s_waitcnt vmcnt(0)" ::: "memory");  // own store at LIC
    if (l == 0)
      __hip_atomic_fetch_add(flagrow + t + 1, 1, __ATOMIC_RELAXED,
                             __HIP_MEMORY_SCOPE_SYSTEM);
    sr = sw;
  }
  c_gl[b_e * 512 + cg * 32 + c2] = cs0;
  c_gl[b_e * 512 + cg * 32 + c2 + 1] = cs1;
}

// ---------------------------------------------------------------------------
// Phase 3: logits + log_softmax (reads final h slot).
// ---------------------------------------------------------------------------
__global__ __launch_bounds__(256) void out_kernel(
    const uint32_t* __restrict__ hfin, const float* __restrict__ Wout,
    const float* __restrict__ bout, float* __restrict__ out) {
  const int b = blockIdx.x, tid = threadIdx.x;
  __shared__ float hrow[512];
  if (tid < 64) {
    int ks = tid >> 2, qq = tid & 3;
    const uint4* h4 = (const uint4*)hfin;
    uint4 v = h4[((((size_t)(b >> 4)) * 16 + ks) * 4 + qq) * 16 + (b & 15)];
    uint32_t u[4] = {v.x, v.y, v.z, v.w};
#pragma unroll
    for (int d = 0; d < 4; ++d) {
      hrow[ks * 32 + qq * 8 + d * 2] = bf2f((unsigned short)(u[d] & 0xffff));
      hrow[ks * 32 + qq * 8 + d * 2 + 1] = bf2f((unsigned short)(u[d] >> 16));
    }
  }
  __syncthreads();
  float acc = bout[tid];
  for (int k = 0; k < 512; ++k) acc += hrow[k] * Wout[k * 256 + tid];
  __shared__ float red[256];
  red[tid] = acc;
  __syncthreads();
  for (int s = 128; s > 0; s >>= 1) {
    if (tid < s) red[tid] = fmaxf(red[tid], red[tid + s]);
    __syncthreads();
  }
  float mx = red[0];
  __syncthreads();
  red[tid] = __expf(acc - mx);
  __syncthreads();
  for (int s = 128; s > 0; s >>= 1) {
    if (tid < s) red[tid] += red[tid + s];
    __syncthreads();
  }
  out[b * 256 + tid] = acc - mx - logf(red[0]);
}

// ---------------------------------------------------------------------------
extern "C" void kernel_launch(void* const* d_in, const int* in_sizes, int n_in,
                              void* d_out, int out_size, void* d_ws,
                              size_t ws_size, hipStream_t stream) {
  const float* X = (const float*)d_in[0];
  const float* Wf = (const float*)d_in[1];
  const float* bf = (const float*)d_in[2];
  const float* Wi = (const float*)d_in[3];
  const float* bi = (const float*)d_in[4];
  const float* Wc = (const float*)d_in[5];
  const float* bc = (const float*)d_in[6];
  const float* Wo = (const float*)d_in[7];
  const float* bo = (const float*)d_in[8];
  const float* Wout = (const float*)d_in[9];
  const float* bout = (const float*)d_in[10];

  char* ws = (char*)d_ws;
  unsigned short* whf = (unsigned short*)(ws + 0x000000);   // 2 MiB
  unsigned short* wxb = (unsigned short*)(ws + 0x200000);   // 1 MiB
  float* bias = (float*)(ws + 0x300000);                    // 8 KiB
  int* flags = (int*)(ws + 0x302000);                       // 33 KiB
  float* c_gl = (float*)(ws + 0x310000);                    // 512 KiB
  uint32_t* h_ex = (uint32_t*)(ws + 0x400000);              // 257 slots x 256 KiB
  const size_t zoff = 0x4500000;                            // 69 MiB
  unsigned short* Z = (unsigned short*)(ws + zoff);         // TC MiB

  int TC = 256;
  while (TC > 16 && zoff + ((size_t)B_SZ * TC * 2048 * 2) > ws_size) TC >>= 1;
  int tcs = 0;
  while ((1 << tcs) < TC) ++tcs;

  pack_kernel<<<(2048 + 256 * 2048 + 1048576 + 255) / 256, 256, 0, stream>>>(
      Wf, Wi, Wc, Wo, bf, bi, bc, bo, whf, wxb, bias);
  init_kernel<<<512, 256, 0, stream>>>(flags, h_ex, c_gl);

  for (int t0 = 0; t0 < T_SEQ; t0 += TC) {
    gemm_x<<<(B_SZ * TC / 128) * 16, 256, 0, stream>>>(X, wxb, bias, Z, t0, TC,
                                                       tcs);
    lstm_chunk<<<256, 256, 0, stream>>>(Z, whf, h_ex, flags, c_gl, t0, TC);
  }
  const int sfin = T_SEQ % (TC + 1);
  out_kernel<<<256, 256, 0, stream>>>(h_ex + (size_t)sfin * 65536, Wout, bout,
                                      (float*)d_out);
}

// Round 4
// 2640.339 us; speedup vs baseline: 3.8003x; 1.1159x over previous
//
#include <hip/hip_runtime.h>
#include <cstdint>

#define B_SZ 256
#define T_SEQ 512
#define I_SZ 256
#define H_SZ 512
#define O_SZ 256

typedef short shortx8 __attribute__((ext_vector_type(8)));
typedef float floatx4 __attribute__((ext_vector_type(4)));
typedef unsigned int uintx4 __attribute__((ext_vector_type(4)));

#define SENT 0xFFFFFFFFu  // bf16 NaN|NaN — unreachable for h in (-1,1)

__device__ __forceinline__ unsigned short f2bf(float f) {
  uint32_t u = __float_as_uint(f);
  u = u + 0x7fffu + ((u >> 16) & 1u);   // RNE
  return (unsigned short)(u >> 16);
}
__device__ __forceinline__ float bf2f(unsigned short h) {
  return __uint_as_float(((uint32_t)h) << 16);
}
__device__ __forceinline__ float sigm(float x) { return 1.0f / (1.0f + __expf(-x)); }
__device__ __forceinline__ float tanh_fast(float x) {
  x = fminf(15.0f, fmaxf(-15.0f, x));
  float e = __expf(2.0f * x);
  return (e - 1.0f) / (e + 1.0f);
}
__device__ __forceinline__ uint32_t umax_(uint32_t a, uint32_t b) {
  return a > b ? a : b;
}
__device__ __forceinline__ uintx4 umax4_(uintx4 a, uintx4 b) {
  uintx4 r;
  r.x = umax_(a.x, b.x); r.y = umax_(a.y, b.y);
  r.z = umax_(a.z, b.z); r.w = umax_(a.w, b.w);
  return r;
}

// ---------------------------------------------------------------------------
// Phase 0: pack weights (unchanged).
// ---------------------------------------------------------------------------
__global__ __launch_bounds__(256) void pack_kernel(
    const float* __restrict__ Wf, const float* __restrict__ Wi,
    const float* __restrict__ Wc, const float* __restrict__ Wo,
    const float* __restrict__ bf, const float* __restrict__ bi,
    const float* __restrict__ bc, const float* __restrict__ bo,
    unsigned short* __restrict__ whf, unsigned short* __restrict__ wx,
    float* __restrict__ bias) {
  int idx = blockIdx.x * 256 + threadIdx.x;
  if (idx < 2048) {
    int g = idx >> 9, hid = idx & 511;
    const float* bp = (g == 0) ? bf : (g == 1) ? bi : (g == 2) ? bc : bo;
    bias[idx] = bp[hid];
  }
  int i2 = idx - 2048;
  if (i2 >= 0 && i2 < 256 * 2048) {
    int k = i2 >> 11, col = i2 & 2047, g = col >> 9, hid = col & 511;
    const float* Wp = (g == 0) ? Wf : (g == 1) ? Wi : (g == 2) ? Wc : Wo;
    wx[i2] = f2bf(Wp[k * 512 + hid]);
  }
  int i3 = i2 - 256 * 2048;
  if (i3 >= 0 && i3 < 1048576) {
    int j = i3 & 7, l = (i3 >> 3) & 63, ks = (i3 >> 9) & 15;
    int nt = (i3 >> 13) & 1, g = (i3 >> 14) & 3, cg = (i3 >> 16) & 15;
    int k = ks * 32 + (l >> 4) * 8 + j;
    int hid = cg * 32 + nt * 16 + (l & 15);
    const float* Wp = (g == 0) ? Wf : (g == 1) ? Wi : (g == 2) ? Wc : Wo;
    whf[i3] = f2bf(Wp[(256 + k) * 512 + hid]);
  }
}

// Init: h slot 0 = zeros (h0), c state = zeros.
__global__ __launch_bounds__(256) void init_kernel(uint32_t* h_ex, float* c_gl) {
  int idx = blockIdx.x * 256 + threadIdx.x;
  if (idx < 65536) h_ex[idx] = 0u;
  if (idx < 131072) c_gl[idx] = 0.0f;
}

// Poison: sentinel-fill all TCp1 slots EXCEPT the live one. One uint4/thread.
__global__ __launch_bounds__(256) void poison_kernel(uint32_t* h_ex, int live,
                                                     int TCp1) {
  size_t idx = (size_t)blockIdx.x * 256 + threadIdx.x;
  if (idx >= (size_t)TCp1 * 16384) return;
  int slot = (int)(idx >> 14);
  if (slot == live) return;
  ((uint4*)h_ex)[idx] = make_uint4(SENT, SENT, SENT, SENT);
}

// ---------------------------------------------------------------------------
// Phase 1: Z = X @ Wx + bias (bf16 out). Unchanged.
// ---------------------------------------------------------------------------
__global__ __launch_bounds__(256) void gemm_x(
    const float* __restrict__ X, const unsigned short* __restrict__ Wx,
    const float* __restrict__ bias, unsigned short* __restrict__ Z,
    int t0, int TC, int tcs) {
  __shared__ unsigned short lds_a[128 * 72];
  __shared__ unsigned short lds_b[128 * 72];
  const int tid = threadIdx.x;
  const int mt = blockIdx.x >> 4, ntb = blockIdx.x & 15;
  const int n0 = ntb * 128;
  const int w = tid >> 6, l = tid & 63, q = l >> 4, n15 = l & 15;

  floatx4 acc[2][8];
#pragma unroll
  for (int a = 0; a < 2; ++a)
#pragma unroll
    for (int nb = 0; nb < 8; ++nb) acc[a][nb] = (floatx4){0.f, 0.f, 0.f, 0.f};

  const int i_row = tid >> 1, half = tid & 1;
  const int Mr = mt * 128 + i_row;
  const int bb = Mr >> tcs, tt = Mr & (TC - 1);
  const float* asrc = X + ((size_t)(bb * T_SEQ + t0 + tt)) * I_SZ;

  for (int ko = 0; ko < 4; ++ko) {
    const int k0 = ko * 64;
    __syncthreads();
#pragma unroll
    for (int u = 0; u < 8; ++u) {
      int kl = half * 32 + u * 4;
      float4 v = *(const float4*)(asrc + k0 + kl);
      uint2 pk;
      pk.x = (uint32_t)f2bf(v.x) | ((uint32_t)f2bf(v.y) << 16);
      pk.y = (uint32_t)f2bf(v.z) | ((uint32_t)f2bf(v.w) << 16);
      *(uint2*)(lds_a + i_row * 72 + kl) = pk;
    }
    {
      int kb = tid >> 4, n8 = (tid & 15) * 8;
#pragma unroll
      for (int p = 0; p < 4; ++p) {
        int kl = p * 16 + kb;
        const unsigned short* srcw = Wx + (size_t)(k0 + kl) * 2048 + n0 + n8;
        uint4 v = *(const uint4*)srcw;
        unsigned short* db = lds_b + kl;
        db[(n8 + 0) * 72] = (unsigned short)(v.x & 0xffff);
        db[(n8 + 1) * 72] = (unsigned short)(v.x >> 16);
        db[(n8 + 2) * 72] = (unsigned short)(v.y & 0xffff);
        db[(n8 + 3) * 72] = (unsigned short)(v.y >> 16);
        db[(n8 + 4) * 72] = (unsigned short)(v.z & 0xffff);
        db[(n8 + 5) * 72] = (unsigned short)(v.z >> 16);
        db[(n8 + 6) * 72] = (unsigned short)(v.w & 0xffff);
        db[(n8 + 7) * 72] = (unsigned short)(v.w >> 16);
      }
    }
    __syncthreads();
#pragma unroll
    for (int kk = 0; kk < 2; ++kk) {
      shortx8 af[2], bfr[8];
#pragma unroll
      for (int a = 0; a < 2; ++a) {
        int row = (w * 2 + a) * 16 + n15;
        af[a] = *(const shortx8*)(lds_a + row * 72 + kk * 32 + q * 8);
      }
#pragma unroll
      for (int nb = 0; nb < 8; ++nb) {
        int col = nb * 16 + n15;
        bfr[nb] = *(const shortx8*)(lds_b + col * 72 + kk * 32 + q * 8);
      }
#pragma unroll
      for (int a = 0; a < 2; ++a)
#pragma unroll
        for (int nb = 0; nb < 8; ++nb)
          acc[a][nb] = __builtin_amdgcn_mfma_f32_16x16x32_bf16(
              af[a], bfr[nb], acc[a][nb], 0, 0, 0);
    }
  }
#pragma unroll
  for (int a = 0; a < 2; ++a) {
#pragma unroll
    for (int nb = 0; nb < 8; ++nb) {
      int colg = n0 + nb * 16 + n15;
      float bv = bias[colg];
      floatx4 v = acc[a][nb];
#pragma unroll
      for (int r = 0; r < 4; ++r) {
        int Mrow = mt * 128 + (w * 2 + a) * 16 + q * 4 + r;
        Z[(size_t)Mrow * 2048 + colg] = f2bf(v[r] + bv);
      }
    }
  }
}

// ---------------------------------------------------------------------------
// Phase 2: recurrent chunk — data-rail sentinel polling, no flags.
//  - consumer: one asm block of 16 global_load_dwordx4 sc0 sc1 (LIC-direct)
//    + vmcnt(0); umax-tree; repeat while any dword == SENT. On success the
//    loaded values ARE the Af fragments (no second load).
//  - producer: gate math then ONE relaxed system store per lane. No vmcnt,
//    no flag, fire-and-forget.
//  - weights: 128 KiB LDS panel (round-3); gate exchange dbuf LDS.
// ---------------------------------------------------------------------------
__global__ __launch_bounds__(256, 1) void lstm_chunk(
    const unsigned short* __restrict__ Z, const unsigned short* __restrict__ whf,
    uint32_t* h_ex, float* c_gl, int t0, int TC) {
  __shared__ unsigned short wlds[65536];   // 128 KiB weight panel
  __shared__ float gl[2][4][16][32];       // 16 KiB gate exchange (dbuf)
  const int tid = threadIdx.x, l = tid & 63, w = tid >> 6, q = l >> 4,
            n15 = l & 15;
  const int bg = blockIdx.x & 15, cg = blockIdx.x >> 4;

  {  // one-time: copy this block's contiguous 128 KiB panel into LDS
    const uint4* src = (const uint4*)(whf + (size_t)cg * 65536);
    uint4* dst = (uint4*)wlds;
#pragma unroll
    for (int i = 0; i < 32; ++i) dst[i * 256 + tid] = src[i * 256 + tid];
  }
  __builtin_amdgcn_fence(__ATOMIC_ACQUIRE, "");  // once per dispatch
  __syncthreads();

  const int m_e = tid >> 4, c2 = (tid & 15) * 2;
  const int b_e = bg * 16 + m_e;
  float cs0 = c_gl[b_e * 512 + cg * 32 + c2];
  float cs1 = c_gl[b_e * 512 + cg * 32 + c2 + 1];

  const unsigned short* wb0 = wlds + w * 16384;  // [ks][lane][8], nt=0
  const unsigned short* wb1 = wb0 + 8192;        // nt=1
  const int TCp1 = TC + 1;
  int sr = t0 % TCp1;  // read slot for step t

  // per-lane element offset (shorts) of Af ks=0 within a slot; ks-stride=512
  const size_t afoff = ((size_t)(bg * 64 + q) * 16 + n15) * 8;

  for (int t = t0; t < t0 + TC; ++t) {
    int sw = sr + 1;
    if (sw == TCp1) sw = 0;
    // Z prefetch (cached; issued before the poll, waited inside it)
    float zv[8];
#pragma unroll
    for (int nt = 0; nt < 2; ++nt)
#pragma unroll
      for (int r = 0; r < 4; ++r)
        zv[nt * 4 + r] =
            bf2f(Z[((size_t)(bg * 16 + q * 4 + r) * TC + (t - t0)) * 2048 +
                   w * 512 + cg * 32 + nt * 16 + n15]);
    // B prefetch ks 0..7 (LDS; overlaps the poll)
    shortx8 bp0[8], bp1[8];
#pragma unroll
    for (int ks = 0; ks < 8; ++ks) {
      bp0[ks] = *(const shortx8*)(wb0 + ks * 512 + l * 8);
      bp1[ks] = *(const shortx8*)(wb1 + ks * 512 + l * 8);
    }

    // ---- data-rail poll: 16x dwordx4 system loads; repeat until no SENT ----
    const unsigned short* hsl =
        (const unsigned short*)(h_ex + (size_t)sr * 65536);
    const unsigned short* pa = hsl + afoff;
    uintx4 A0, A1, A2, A3, A4, A5, A6, A7, A8, A9, A10, A11, A12, A13, A14, A15;
    uint32_t mx;
    do {
      asm volatile(
          "global_load_dwordx4 %0, %16, off sc0 sc1\n\t"
          "global_load_dwordx4 %1, %16, off offset:1024 sc0 sc1\n\t"
          "global_load_dwordx4 %2, %16, off offset:2048 sc0 sc1\n\t"
          "global_load_dwordx4 %3, %16, off offset:3072 sc0 sc1\n\t"
          "global_load_dwordx4 %4, %17, off sc0 sc1\n\t"
          "global_load_dwordx4 %5, %17, off offset:1024 sc0 sc1\n\t"
          "global_load_dwordx4 %6, %17, off offset:2048 sc0 sc1\n\t"
          "global_load_dwordx4 %7, %17, off offset:3072 sc0 sc1\n\t"
          "global_load_dwordx4 %8, %18, off sc0 sc1\n\t"
          "global_load_dwordx4 %9, %18, off offset:1024 sc0 sc1\n\t"
          "global_load_dwordx4 %10, %18, off offset:2048 sc0 sc1\n\t"
          "global_load_dwordx4 %11, %18, off offset:3072 sc0 sc1\n\t"
          "global_load_dwordx4 %12, %19, off sc0 sc1\n\t"
          "global_load_dwordx4 %13, %19, off offset:1024 sc0 sc1\n\t"
          "global_load_dwordx4 %14, %19, off offset:2048 sc0 sc1\n\t"
          "global_load_dwordx4 %15, %19, off offset:3072 sc0 sc1\n\t"
          "s_waitcnt vmcnt(0)"
          : "=v"(A0), "=v"(A1), "=v"(A2), "=v"(A3), "=v"(A4), "=v"(A5),
            "=v"(A6), "=v"(A7), "=v"(A8), "=v"(A9), "=v"(A10), "=v"(A11),
            "=v"(A12), "=v"(A13), "=v"(A14), "=v"(A15)
          : "v"(pa), "v"(pa + 2048), "v"(pa + 4096), "v"(pa + 6144)
          : "memory");
      uintx4 m = umax4_(umax4_(umax4_(A0, A1), umax4_(A2, A3)),
                        umax4_(umax4_(A4, A5), umax4_(A6, A7)));
      m = umax4_(m, umax4_(umax4_(A8, A9), umax4_(A10, A11)));
      m = umax4_(m, umax4_(umax4_(A12, A13), umax4_(A14, A15)));
      mx = umax_(umax_(m.x, m.y), umax_(m.z, m.w));
    } while (__any(mx == SENT));

    uintx4 Au[16] = {A0, A1, A2,  A3,  A4,  A5,  A6,  A7,
                     A8, A9, A10, A11, A12, A13, A14, A15};
    floatx4 a0 = (floatx4){0.f, 0.f, 0.f, 0.f};
    floatx4 a1 = (floatx4){0.f, 0.f, 0.f, 0.f};
#pragma unroll
    for (int ks = 0; ks < 8; ++ks) {
      shortx8 af = *(shortx8*)&Au[ks];
      a0 = __builtin_amdgcn_mfma_f32_16x16x32_bf16(af, bp0[ks], a0, 0, 0, 0);
      a1 = __builtin_amdgcn_mfma_f32_16x16x32_bf16(af, bp1[ks], a1, 0, 0, 0);
    }
#pragma unroll
    for (int ks = 8; ks < 16; ++ks) {
      shortx8 af = *(shortx8*)&Au[ks];
      shortx8 tb0 = *(const shortx8*)(wb0 + ks * 512 + l * 8);
      shortx8 tb1 = *(const shortx8*)(wb1 + ks * 512 + l * 8);
      a0 = __builtin_amdgcn_mfma_f32_16x16x32_bf16(af, tb0, a0, 0, 0, 0);
      a1 = __builtin_amdgcn_mfma_f32_16x16x32_bf16(af, tb1, a1, 0, 0, 0);
    }
    // gate nonlinearity, publish to LDS (buffer t&1)
    const int pb = t & 1;
#pragma unroll
    for (int i = 0; i < 8; ++i) {
      float x = ((i < 4) ? a0[i & 3] : a1[i & 3]) + zv[i];
      float gv = (w == 2) ? tanh_fast(x) : sigm(x);
      gl[pb][w][q * 4 + (i & 3)][(i >> 2) * 16 + n15] = gv;
    }
    __syncthreads();
    {
      float f0 = gl[pb][0][m_e][c2], f1 = gl[pb][0][m_e][c2 + 1];
      float i0 = gl[pb][1][m_e][c2], i1 = gl[pb][1][m_e][c2 + 1];
      float g0 = gl[pb][2][m_e][c2], g1 = gl[pb][2][m_e][c2 + 1];
      float o0 = gl[pb][3][m_e][c2], o1 = gl[pb][3][m_e][c2 + 1];
      cs0 = f0 * cs0 + i0 * g0;
      cs1 = f1 * cs1 + i1 * g1;
      float h0 = o0 * tanh_fast(cs0);
      float h1 = o1 * tanh_fast(cs1);
      uint32_t hw = (uint32_t)f2bf(h0) | ((uint32_t)f2bf(h1) << 16);
      size_t widx = (size_t)sw * 65536 +
                    (size_t)(((bg * 16 + cg) * 4 + (c2 >> 3)) * 16 + m_e) * 4 +
                    ((c2 & 7) >> 1);
      __hip_atomic_store(h_ex + widx, hw, __ATOMIC_RELAXED,
                         __HIP_MEMORY_SCOPE_SYSTEM);  // fire-and-forget
    }
    sr = sw;
  }
  c_gl[b_e * 512 + cg * 32 + c2] = cs0;
  c_gl[b_e * 512 + cg * 32 + c2 + 1] = cs1;
}

// ---------------------------------------------------------------------------
// Phase 3: logits + log_softmax (reads final h slot). Unchanged.
// ---------------------------------------------------------------------------
__global__ __launch_bounds__(256) void out_kernel(
    const uint32_t* __restrict__ hfin, const float* __restrict__ Wout,
    const float* __restrict__ bout, float* __restrict__ out) {
  const int b = blockIdx.x, tid = threadIdx.x;
  __shared__ float hrow[512];
  if (tid < 64) {
    int ks = tid >> 2, qq = tid & 3;
    const uint4* h4 = (const uint4*)hfin;
    uint4 v = h4[((((size_t)(b >> 4)) * 16 + ks) * 4 + qq) * 16 + (b & 15)];
    uint32_t u[4] = {v.x, v.y, v.z, v.w};
#pragma unroll
    for (int d = 0; d < 4; ++d) {
      hrow[ks * 32 + qq * 8 + d * 2] = bf2f((unsigned short)(u[d] & 0xffff));
      hrow[ks * 32 + qq * 8 + d * 2 + 1] = bf2f((unsigned short)(u[d] >> 16));
    }
  }
  __syncthreads();
  float acc = bout[tid];
  for (int k = 0; k < 512; ++k) acc += hrow[k] * Wout[k * 256 + tid];
  __shared__ float red[256];
  red[tid] = acc;
  __syncthreads();
  for (int s = 128; s > 0; s >>= 1) {
    if (tid < s) red[tid] = fmaxf(red[tid], red[tid + s]);
    __syncthreads();
  }
  float mx = red[0];
  __syncthreads();
  red[tid] = __expf(acc - mx);
  __syncthreads();
  for (int s = 128; s > 0; s >>= 1) {
    if (tid < s) red[tid] += red[tid + s];
    __syncthreads();
  }
  out[b * 256 + tid] = acc - mx - logf(red[0]);
}

// ---------------------------------------------------------------------------
extern "C" void kernel_launch(void* const* d_in, const int* in_sizes, int n_in,
                              void* d_out, int out_size, void* d_ws,
                              size_t ws_size, hipStream_t stream) {
  const float* X = (const float*)d_in[0];
  const float* Wf = (const float*)d_in[1];
  const float* bf = (const float*)d_in[2];
  const float* Wi = (const float*)d_in[3];
  const float* bi = (const float*)d_in[4];
  const float* Wc = (const float*)d_in[5];
  const float* bc = (const float*)d_in[6];
  const float* Wo = (const float*)d_in[7];
  const float* bo = (const float*)d_in[8];
  const float* Wout = (const float*)d_in[9];
  const float* bout = (const float*)d_in[10];

  char* ws = (char*)d_ws;
  unsigned short* whf = (unsigned short*)(ws + 0x000000);   // 2 MiB
  unsigned short* wxb = (unsigned short*)(ws + 0x200000);   // 1 MiB
  float* bias = (float*)(ws + 0x300000);                    // 8 KiB
  float* c_gl = (float*)(ws + 0x310000);                    // 512 KiB
  uint32_t* h_ex = (uint32_t*)(ws + 0x400000);              // 257 x 256 KiB
  const size_t zoff = 0x4500000;                            // 69 MiB
  unsigned short* Z = (unsigned short*)(ws + zoff);         // TC MiB

  int TC = 256;
  while (TC > 16 && zoff + ((size_t)B_SZ * TC * 2048 * 2) > ws_size) TC >>= 1;
  int tcs = 0;
  while ((1 << tcs) < TC) ++tcs;
  const int TCp1 = TC + 1;

  pack_kernel<<<(2048 + 256 * 2048 + 1048576 + 255) / 256, 256, 0, stream>>>(
      Wf, Wi, Wc, Wo, bf, bi, bc, bo, whf, wxb, bias);
  init_kernel<<<512, 256, 0, stream>>>(h_ex, c_gl);

  for (int t0 = 0; t0 < T_SEQ; t0 += TC) {
    poison_kernel<<<(TCp1 * 16384 + 255) / 256, 256, 0, stream>>>(
        h_ex, t0 % TCp1, TCp1);
    gemm_x<<<(B_SZ * TC / 128) * 16, 256, 0, stream>>>(X, wxb, bias, Z, t0, TC,
                                                       tcs);
    lstm_chunk<<<256, 256, 0, stream>>>(Z, whf, h_ex, c_gl, t0, TC);
  }
  const int sfin = T_SEQ % TCp1;
  out_kernel<<<256, 256, 0, stream>>>(h_ex + (size_t)sfin * 65536, Wout, bout,
                                      (float*)d_out);
}